// Round 1
// baseline (371.593 us; speedup 1.0000x reference)
//
#include <hip/hip_runtime.h>
#include <math.h>
#include <float.h>

#define NN 1024
#define DD 128
#define HH 8
#define HDIM 16
#define KTOP 16

__device__ __forceinline__ float wred_sum(float v) {
#pragma unroll
  for (int off = 32; off > 0; off >>= 1) v += __shfl_xor(v, off, 64);
  return v;
}

// ---------------- K1: q,k,v = h @ W{q,k,v} + b ----------------
__global__ __launch_bounds__(128) void k_qkv(
    const float* __restrict__ h,
    const float* __restrict__ Wq, const float* __restrict__ bq,
    const float* __restrict__ Wk, const float* __restrict__ bk,
    const float* __restrict__ Wv, const float* __restrict__ bv,
    float* __restrict__ q, float* __restrict__ k, float* __restrict__ v) {
  __shared__ float hrow[4][DD];
  const int t = threadIdx.x;
  const int i0 = blockIdx.x * 4;
#pragma unroll
  for (int r = 0; r < 4; ++r) hrow[r][t] = h[(i0 + r) * DD + t];
  __syncthreads();
  const float* W[3] = {Wq, Wk, Wv};
  const float* B[3] = {bq, bk, bv};
  float* O[3] = {q, k, v};
#pragma unroll
  for (int m = 0; m < 3; ++m) {
    float a0 = 0.f, a1 = 0.f, a2 = 0.f, a3 = 0.f;
    const float* Wm = W[m];
#pragma unroll 8
    for (int c = 0; c < DD; ++c) {
      float w = Wm[c * DD + t];
      a0 += hrow[0][c] * w; a1 += hrow[1][c] * w;
      a2 += hrow[2][c] * w; a3 += hrow[3][c] * w;
    }
    float b = B[m][t];
    float* Om = O[m];
    Om[(i0 + 0) * DD + t] = a0 + b;
    Om[(i0 + 1) * DD + t] = a1 + b;
    Om[(i0 + 2) * DD + t] = a2 + b;
    Om[(i0 + 3) * DD + t] = a3 + b;
  }
}

// ---------------- K2: fused scores + top-k + softmax + PV ----------------
// one block per node i; streams e[i,:,:] (512 KB) once.
__global__ __launch_bounds__(256) void k_attn(
    const float* __restrict__ e, const float* __restrict__ We, const float* __restrict__ be,
    const float* __restrict__ q, const float* __restrict__ k, const float* __restrict__ v,
    float* __restrict__ hattn) {
  __shared__ float sc[NN * HH];                    // 32 KB, stride 8 (write conflict-free)
  __shared__ __align__(16) float WeT[HH * 136];    // padded: 2-way (free) on b128 reads
  __shared__ __align__(16) float qrow[DD];
  __shared__ float beS[HH];
  const int tid = threadIdx.x;
  const int lane = tid & 63;
  const int wv = tid >> 6;
  const int i = blockIdx.x;

  for (int idx = tid; idx < DD * HH; idx += 256) {
    int c = idx >> 3, hh2 = idx & 7;
    WeT[hh2 * 136 + c] = We[c * HH + hh2];
  }
  if (tid < DD) qrow[tid] = q[i * DD + tid] * 0.25f;  // 1/sqrt(HD)
  if (tid < HH) beS[tid] = be[tid];
  __syncthreads();

  const int jsub = lane >> 3;
  const int hh = lane & 7;
  const float* wrow = &WeT[hh * 136];

  // ---- phase 2: scores[j][h] = e[i,j,:]@We[:,h] + be[h] + (q.k)/4 ----
  for (int j0 = 0; j0 < NN; j0 += 128) {
    const int jb = j0 + wv * 32 + jsub;            // lane owns j = jb + {0,8,16,24}
    const float* eb = e + ((size_t)i << 17) + (size_t)jb * DD;
    float b0 = beS[hh];
    float a0 = b0, a1 = b0, a2 = b0, a3 = b0;
#pragma unroll 4
    for (int c4 = 0; c4 < 32; ++c4) {
      float4 w4 = *(const float4*)(wrow + c4 * 4);
      float4 e0 = *(const float4*)(eb + c4 * 4);
      float4 e1 = *(const float4*)(eb + 1024 + c4 * 4);
      float4 e2 = *(const float4*)(eb + 2048 + c4 * 4);
      float4 e3 = *(const float4*)(eb + 3072 + c4 * 4);
      a0 += e0.x * w4.x + e0.y * w4.y + e0.z * w4.z + e0.w * w4.w;
      a1 += e1.x * w4.x + e1.y * w4.y + e1.z * w4.z + e1.w * w4.w;
      a2 += e2.x * w4.x + e2.y * w4.y + e2.z * w4.z + e2.w * w4.w;
      a3 += e3.x * w4.x + e3.y * w4.y + e3.z * w4.z + e3.w * w4.w;
    }
    float acc[4] = {a0, a1, a2, a3};
#pragma unroll
    for (int m = 0; m < 4; ++m) {
      const int j = jb + m * 8;
      const float* kp = k + (size_t)j * DD + hh * HDIM;
      const float* qp = &qrow[hh * HDIM];
      float d0 = 0.f;
#pragma unroll
      for (int x = 0; x < 4; ++x) {
        float4 kv4 = *(const float4*)(kp + x * 4);
        float4 qv4 = *(const float4*)(qp + x * 4);
        d0 += kv4.x * qv4.x + kv4.y * qv4.y + kv4.z * qv4.z + kv4.w * qv4.w;
      }
      sc[j * HH + hh] = acc[m] + d0;
    }
  }
  __syncthreads();

  // ---- phase 3: per head: top-16 (lowest-j tie-break), softmax, PV ----
#pragma unroll 1
  for (int hp = 0; hp < 2; ++hp) {
    const int h = wv + hp * 4;
    float val[16];
#pragma unroll
    for (int s = 0; s < 16; ++s) val[s] = sc[(s * 64 + lane) * HH + h];
    int selj[16];
    float wgt[16];
    float vmax = 0.f, denom = 0.f;
#pragma unroll
    for (int t = 0; t < KTOP; ++t) {
      float bv = -FLT_MAX;
      int bj = 0x7FFFFFFF;
#pragma unroll
      for (int s = 0; s < 16; ++s) {
        float vs = val[s];
        int jj = s * 64 + lane;
        if (vs > bv) { bv = vs; bj = jj; }   // ascending s => lowest j kept on ties
      }
#pragma unroll
      for (int off = 32; off > 0; off >>= 1) {
        float ov = __shfl_xor(bv, off, 64);
        int oj = __shfl_xor(bj, off, 64);
        if (ov > bv || (ov == bv && oj < bj)) { bv = ov; bj = oj; }
      }
      selj[t] = bj;
      if (t == 0) vmax = bv;
      float w = expf(bv - vmax);
      wgt[t] = w;
      denom += w;
      const int so = bj >> 6;
      if ((bj & 63) == lane) {
#pragma unroll
        for (int s = 0; s < 16; ++s)
          if (s == so) val[s] = -FLT_MAX;   // static index only (no scratch)
      }
    }
    const float inv = 1.0f / denom;
    const int d = lane & 15;
    float acc = 0.f;
#pragma unroll
    for (int t = 0; t < KTOP; ++t)
      acc += wgt[t] * v[(size_t)selj[t] * DD + h * HDIM + d];
    if (lane < 16) hattn[i * DD + h * HDIM + d] = acc * inv;
  }
}

// ---------------- K3: Wo proj + residual + LN1 + LSTMCell(zero state) ----------------
__global__ __launch_bounds__(128) void k_post1(
    const float* __restrict__ h, const float* __restrict__ hattn,
    const float* __restrict__ Wo, const float* __restrict__ bo,
    const float* __restrict__ Wih, const float* __restrict__ bih, const float* __restrict__ bhh,
    const float* __restrict__ ln1g, const float* __restrict__ ln1b,
    float* __restrict__ x2, float* __restrict__ outh, float* __restrict__ outc) {
  __shared__ float arow[4][DD];
  __shared__ float x1s[4][DD];
  __shared__ float redS[4][2], redQ[4][2];
  const int t = threadIdx.x;
  const int i0 = blockIdx.x * 4;
#pragma unroll
  for (int r = 0; r < 4; ++r) arow[r][t] = hattn[(i0 + r) * DD + t];
  __syncthreads();
  float o0 = 0.f, o1 = 0.f, o2 = 0.f, o3 = 0.f;
#pragma unroll 4
  for (int c = 0; c < DD; ++c) {
    float w = Wo[c * DD + t];
    o0 += arow[0][c] * w; o1 += arow[1][c] * w;
    o2 += arow[2][c] * w; o3 += arow[3][c] * w;
  }
  float ovals[4] = {o0, o1, o2, o3};
  const float bov = bo[t], g1 = ln1g[t], b1 = ln1b[t];
#pragma unroll
  for (int r = 0; r < 4; ++r) {
    float res = h[(i0 + r) * DD + t] + ovals[r] + bov;
    float s1 = wred_sum(res), s2 = wred_sum(res * res);
    if ((t & 63) == 0) { redS[r][t >> 6] = s1; redQ[r][t >> 6] = s2; }
    __syncthreads();
    float mu = (redS[r][0] + redS[r][1]) * (1.f / 128.f);
    float var = (redQ[r][0] + redQ[r][1]) * (1.f / 128.f) - mu * mu;
    x1s[r][t] = g1 * (res - mu) * rsqrtf(var + 1e-5f) + b1;
  }
  __syncthreads();
  // gates = x1 @ Wih^T + bih + bhh ; order i,f,g,o ; f unused (c_prev = 0)
  float gi[4] = {0, 0, 0, 0}, gg[4] = {0, 0, 0, 0}, go[4] = {0, 0, 0, 0};
  for (int c = 0; c < DD; ++c) {
    float wI = Wih[(t)*DD + c];
    float wG = Wih[(t + 256) * DD + c];
    float wO = Wih[(t + 384) * DD + c];
#pragma unroll
    for (int r = 0; r < 4; ++r) {
      float xv = x1s[r][c];
      gi[r] += xv * wI; gg[r] += xv * wG; go[r] += xv * wO;
    }
  }
  const float biI = bih[t] + bhh[t];
  const float biG = bih[t + 256] + bhh[t + 256];
  const float biO = bih[t + 384] + bhh[t + 384];
#pragma unroll
  for (int r = 0; r < 4; ++r) {
    float iv = 1.f / (1.f + expf(-(gi[r] + biI)));
    float gv = tanhf(gg[r] + biG);
    float ov = 1.f / (1.f + expf(-(go[r] + biO)));
    float cn = iv * gv;
    float hn = ov * tanhf(cn);
    outh[(i0 + r) * DD + t] = hn;
    outc[(i0 + r) * DD + t] = cn;
    x2[(i0 + r) * DD + t] = x1s[r][t] + hn;
  }
}

// ---------------- K4: GraphNorm column stats over node dim ----------------
__global__ __launch_bounds__(1024) void k_gnstats(const float* __restrict__ x2,
                                                  float* __restrict__ stats) {
  __shared__ float S[8][DD], Q[8][DD];
  const int t = threadIdx.x;
  const int c = t & 127, g = t >> 7;
  float s = 0.f, qq = 0.f;
  for (int r = g * 128; r < g * 128 + 128; ++r) {
    float v = x2[r * DD + c];
    s += v; qq += v * v;
  }
  S[g][c] = s; Q[g][c] = qq;
  __syncthreads();
  if (g == 0) {
    float ss = 0.f, sq = 0.f;
#pragma unroll
    for (int kk = 0; kk < 8; ++kk) { ss += S[kk][c]; sq += Q[kk][c]; }
    float mu = ss * (1.f / 1024.f);
    float var = sq * (1.f / 1024.f) - mu * mu;
    stats[c] = mu;
    stats[DD + c] = rsqrtf(var + 1e-5f);
  }
}

// ---------------- K5: GraphNorm apply + FFN + residual + LN2 ----------------
__global__ __launch_bounds__(256) void k_ffn(
    const float* __restrict__ x2, const float* __restrict__ stats,
    const float* __restrict__ gng, const float* __restrict__ gnb,
    const float* __restrict__ Wf1, const float* __restrict__ bf1,
    const float* __restrict__ Wf2, const float* __restrict__ bf2,
    const float* __restrict__ ln2g, const float* __restrict__ ln2b,
    float* __restrict__ out) {
  __shared__ float x3s[4][DD];
  __shared__ float hid[4][512];
  __shared__ float redC[4][256];
  __shared__ float redS[4][4], redQ[4][4];
  const int t = threadIdx.x;
  const int i0 = blockIdx.x * 4;
  for (int idx = t; idx < 4 * DD; idx += 256) {
    int r = idx >> 7, c = idx & 127;
    float vv = x2[(i0 + r) * DD + c];
    x3s[r][c] = gng[c] * (vv - stats[c]) * stats[DD + c] + gnb[c];
  }
  __syncthreads();
  {
    float a0[4] = {0, 0, 0, 0}, a1[4] = {0, 0, 0, 0};
#pragma unroll 2
    for (int c = 0; c < DD; ++c) {
      float w1 = Wf1[c * 512 + t];
      float w2 = Wf1[c * 512 + t + 256];
#pragma unroll
      for (int r = 0; r < 4; ++r) {
        float xv = x3s[r][c];
        a0[r] += xv * w1; a1[r] += xv * w2;
      }
    }
    float bb1 = bf1[t], bb2 = bf1[t + 256];
#pragma unroll
    for (int r = 0; r < 4; ++r) {
      hid[r][t] = fmaxf(a0[r] + bb1, 0.f);
      hid[r][t + 256] = fmaxf(a1[r] + bb2, 0.f);
    }
  }
  __syncthreads();
  const int d = t & 127, half = t >> 7;
  {
    float a[4] = {0, 0, 0, 0};
    for (int uu = 0; uu < 256; ++uu) {
      int u = half * 256 + uu;
      float w = Wf2[u * DD + d];
#pragma unroll
      for (int r = 0; r < 4; ++r) a[r] += hid[r][u] * w;
    }
#pragma unroll
    for (int r = 0; r < 4; ++r) redC[r][t] = a[r];
  }
  __syncthreads();
  const int lane = t & 63, wvv = t >> 6;
#pragma unroll 1
  for (int r = 0; r < 4; ++r) {
    float z = 0.f;
    if (t < DD) z = x3s[r][t] + redC[r][t] + redC[r][t + 128] + bf2[t];
    float s1 = wred_sum(z), s2 = wred_sum(z * z);
    if (lane == 0) { redS[r][wvv] = s1; redQ[r][wvv] = s2; }
    __syncthreads();
    float sum = redS[r][0] + redS[r][1] + redS[r][2] + redS[r][3];
    float sq = redQ[r][0] + redQ[r][1] + redQ[r][2] + redQ[r][3];
    float mu = sum * (1.f / 128.f);
    float var = sq * (1.f / 128.f) - mu * mu;
    float rs = rsqrtf(var + 1e-5f);
    if (t < DD) out[(i0 + r) * DD + t] = ln2g[t] * (z - mu) * rs + ln2b[t];
  }
}

extern "C" void kernel_launch(void* const* d_in, const int* in_sizes, int n_in,
                              void* d_out, int out_size, void* d_ws, size_t ws_size,
                              hipStream_t stream) {
  const float* h   = (const float*)d_in[0];
  const float* e   = (const float*)d_in[1];
  // d_in[2] adjm_bin: unused by reference
  const float* Wq  = (const float*)d_in[3];
  const float* bq  = (const float*)d_in[4];
  const float* Wk  = (const float*)d_in[5];
  const float* bk  = (const float*)d_in[6];
  const float* Wv  = (const float*)d_in[7];
  const float* bv  = (const float*)d_in[8];
  const float* We  = (const float*)d_in[9];
  const float* be  = (const float*)d_in[10];
  const float* Wo  = (const float*)d_in[11];
  const float* bo  = (const float*)d_in[12];
  const float* Wf1 = (const float*)d_in[13];
  const float* bf1 = (const float*)d_in[14];
  const float* Wf2 = (const float*)d_in[15];
  const float* bf2 = (const float*)d_in[16];
  const float* Wih = (const float*)d_in[17];
  // d_in[18] Whh: unused (zero initial hidden state)
  const float* bih = (const float*)d_in[19];
  const float* bhh = (const float*)d_in[20];
  const float* gng = (const float*)d_in[21];
  const float* gnb = (const float*)d_in[22];
  const float* l1g = (const float*)d_in[23];
  const float* l1b = (const float*)d_in[24];
  const float* l2g = (const float*)d_in[25];
  const float* l2b = (const float*)d_in[26];

  float* W = (float*)d_ws;
  float* q     = W;
  float* k     = W + 131072;
  float* v     = W + 262144;
  float* hattn = W + 393216;
  float* x2    = W + 524288;
  float* stats = W + 655360;

  float* out  = (float*)d_out;
  float* outh = out + 131072;
  float* outc = out + 262144;

  hipLaunchKernelGGL(k_qkv, dim3(256), dim3(128), 0, stream,
                     h, Wq, bq, Wk, bk, Wv, bv, q, k, v);
  hipLaunchKernelGGL(k_attn, dim3(1024), dim3(256), 0, stream,
                     e, We, be, q, k, v, hattn);
  hipLaunchKernelGGL(k_post1, dim3(256), dim3(128), 0, stream,
                     h, hattn, Wo, bo, Wih, bih, bhh, l1g, l1b, x2, outh, outc);
  hipLaunchKernelGGL(k_gnstats, dim3(1), dim3(1024), 0, stream, x2, stats);
  hipLaunchKernelGGL(k_ffn, dim3(256), dim3(256), 0, stream,
                     x2, stats, gng, gnb, Wf1, bf1, Wf2, bf2, l2g, l2b, out);
}